// Round 14
// baseline (677.645 us; speedup 1.0000x reference)
//
#include <hip/hip_runtime.h>
#include <hip/hip_bf16.h>

#define BATCH   16
#define N_ANC   8649      // 31*31*9
#define SORT_N  16384     // padded pow2
#define PRE     6000
#define POST    1500
#define ROWW    188       // u32 words per mask row (752 B, 47 uint4)
#define MROWS   6016      // rows incl. 16 pad rows (group 187)
#define NGRP    188       // 188 groups of 32 rows
#define GBYTES  24064     // bytes per 32-row group (32*188*4)
#define TI      256
#define TJ      256

// ---------------- Kernel 1: decode boxes + build sort keys ----------------
__global__ __launch_bounds__(256) void k_decode(
    const float* __restrict__ deltas, const float* __restrict__ probs,
    const float* __restrict__ anchors, float4* __restrict__ boxes,
    unsigned long long* __restrict__ keys)
{
    int t = blockIdx.x * 256 + threadIdx.x;
    if (t >= BATCH * SORT_N) return;
    int b = t / SORT_N;
    int n = t - b * SORT_N;
    if (n >= N_ANC) { keys[t] = ~0ULL; return; }

    float s = probs[(size_t)b * N_ANC + n];
    unsigned int bits = __float_as_uint(s);
    unsigned int u = bits ^ ((bits & 0x80000000u) ? 0xFFFFFFFFu : 0x80000000u);
    keys[(size_t)b * SORT_N + n] = ((unsigned long long)(~u) << 32) | (unsigned int)n;

    float4 a = ((const float4*)anchors)[n];
    float4 d = ((const float4*)deltas)[(size_t)b * N_ANC + n];
    float dy = d.x * 0.1f, dx = d.y * 0.1f, dh = d.z * 0.2f, dw = d.w * 0.2f;
    float ah = a.z - a.x, aw = a.w - a.y;
    float cy = a.x + 0.5f * ah, cx = a.y + 0.5f * aw;
    float bh = expf(dh) * ah, bw = expf(dw) * aw;
    float bcy = dy * ah + cy, bcx = dx * aw + cx;
    float y1 = bcy - 0.5f * bh, x1 = bcx - 0.5f * bw;
    boxes[(size_t)b * N_ANC + n] = make_float4(y1, x1, y1 + bh, x1 + bw);
}

// ---------------- Kernel 2a: per-chunk bitonic sort (2 blocks / batch) ----------------
__global__ __launch_bounds__(1024) void k_sort_chunk(unsigned long long* __restrict__ keys)
{
    __shared__ unsigned long long sb[8192];   // 64 KB
    int b = blockIdx.x >> 1;
    int c = blockIdx.x & 1;
    unsigned long long* g = keys + (size_t)b * SORT_N + c * 8192;

    for (int t = threadIdx.x; t < 8192; t += 1024) sb[t] = g[t];
    __syncthreads();
    for (int k = 2; k <= 8192; k <<= 1) {
        for (int j = k >> 1; j >= 1; j >>= 1) {
            for (int p = threadIdx.x; p < 4096; p += 1024) {
                int i  = ((p & ~(j - 1)) << 1) | (p & (j - 1));
                int gi = (c << 13) | i;
                bool asc = ((gi & k) == 0);
                unsigned long long a = sb[i], b2 = sb[i | j];
                bool sw = asc ? (a > b2) : (a < b2);
                if (sw) { sb[i] = b2; sb[i | j] = a; }
            }
            __syncthreads();
        }
    }
    for (int t = threadIdx.x; t < 8192; t += 1024) g[t] = sb[t];
}

// ---------------- Kernel 2b: merge (1 block / batch), keep top 6016 ----------------
__global__ __launch_bounds__(1024) void k_sort_merge(unsigned long long* __restrict__ keys)
{
    __shared__ unsigned long long sb[8192];   // 64 KB
    int b = blockIdx.x;
    unsigned long long* kb = keys + (size_t)b * SORT_N;

    for (int p = threadIdx.x; p < 8192; p += 1024) {
        unsigned long long a = kb[p], b2 = kb[p + 8192];
        if (a > b2) { kb[p] = b2; kb[p + 8192] = a; }
    }
    __syncthreads();

    for (int t = threadIdx.x; t < 8192; t += 1024) sb[t] = kb[t];
    __syncthreads();
    for (int j = 4096; j >= 1; j >>= 1) {
        for (int p = threadIdx.x; p < 4096; p += 1024) {
            int i = ((p & ~(j - 1)) << 1) | (p & (j - 1));
            unsigned long long a = sb[i], b2 = sb[i | j];
            if (a > b2) { sb[i] = b2; sb[i | j] = a; }
        }
        __syncthreads();
    }
    for (int t = threadIdx.x; t < 6016; t += 1024) kb[t] = sb[t];
}

// ---------------- Kernel 3: gather sorted boxes/scores ----------------
__global__ __launch_bounds__(256) void k_gather(
    const unsigned long long* __restrict__ keys, const float4* __restrict__ boxes,
    const float* __restrict__ probs,
    float4* __restrict__ sboxes, float* __restrict__ sscores)
{
    int t = blockIdx.x * 256 + threadIdx.x;
    if (t >= BATCH * PRE) return;
    int b = t / PRE;
    int r = t - b * PRE;
    unsigned long long k = keys[(size_t)b * SORT_N + r];
    int idx = (int)(k & 0xFFFFFFFFu);
    sboxes[(size_t)b * PRE + r]  = boxes[(size_t)b * N_ANC + idx];
    sscores[(size_t)b * PRE + r] = probs[(size_t)b * N_ANC + idx];
}

// ---------------- Kernel 4: IoU bit-matrix (round-13 form: fma-sign decision) ------
template<bool PRED>
__device__ __forceinline__ unsigned int iou_word(
    const float4* __restrict__ jb, const float* __restrict__ ja,
    int wq, float4 bi, float ai, int trow)
{
    unsigned int bits = 0u, band = 0u;
    #pragma unroll
    for (int jj = 0; jj < 32; jj++) {
        int lj = wq * 32 + jj;
        float4 bx = jb[lj];
        float ih = fmaxf(fminf(bi.z, bx.z) - fmaxf(bi.x, bx.x), 0.0f);
        float iw = fmaxf(fminf(bi.w, bx.w) - fmaxf(bi.y, bx.y), 0.0f);
        float inter = ih * iw;
        float denom = ai + ja[lj] - inter + 1e-8f;
        float tt = __builtin_fmaf(-0.7f, denom, inter);
        bool pred = (!PRED) || (lj > trow);
        if ((tt > 0.0f) && pred) bits |= (1u << jj);
        if ((fabsf(tt) < denom * 3e-7f) && pred) band |= (1u << jj);
    }
    if (band) {                              // cold: exact-path fixup
        #pragma unroll 1
        for (int jj = 0; jj < 32; jj++) {
            if ((band >> jj) & 1u) {
                int lj = wq * 32 + jj;
                float4 bx = jb[lj];
                float ih = fmaxf(fminf(bi.z, bx.z) - fmaxf(bi.x, bx.x), 0.0f);
                float iw = fmaxf(fminf(bi.w, bx.w) - fmaxf(bi.y, bx.y), 0.0f);
                float inter = ih * iw;
                float denom = ai + ja[lj] - inter + 1e-8f;
                if (inter / denom > 0.7f) bits |= (1u << jj);
                else                      bits &= ~(1u << jj);
            }
        }
    }
    return bits;
}

__global__ __launch_bounds__(256) void k_iou(
    const float4* __restrict__ sboxes, unsigned int* __restrict__ mask)
{
    int it = blockIdx.x;   // row tile 0..23
    int jt = blockIdx.y;   // col tile 0..23
    int b  = blockIdx.z;
    if (jt < it) return;   // lower-triangle tiles never consumed by scan

    __shared__ float4 jb[TJ];
    __shared__ float  ja[TJ];
    int t = threadIdx.x;
    int j = jt * TJ + t;
    float4 bj = (j < PRE) ? sboxes[(size_t)b * PRE + j]
                          : make_float4(-2e6f, -2e6f, -1.5e6f, -1.5e6f); // far dummy, area>0
    jb[t] = bj;
    ja[t] = (bj.z - bj.x) * (bj.w - bj.y);
    __syncthreads();

    int i = it * TI + t;
    if (i >= PRE) return;
    float4 bi = sboxes[(size_t)b * PRE + i];
    float areai = (bi.z - bi.x) * (bi.w - bi.y);

    unsigned int w[8];
    if (jt > it) {
        for (int wq = 0; wq < 8; wq++)
            w[wq] = iou_word<false>(jb, ja, wq, bi, areai, 0);
    } else {
        for (int wq = 0; wq < 8; wq++) {
            int jbase = jt * TJ + wq * 32;
            w[wq] = (jbase + 31 > i) ? iou_word<true>(jb, ja, wq, bi, areai, t) : 0u;
        }
    }

    unsigned int* row = mask + ((size_t)b * MROWS + i) * ROWW + jt * 8;
    ((uint4*)row)[0] = make_uint4(w[0], w[1], w[2], w[3]);
    if (jt < 23) ((uint4*)row)[1] = make_uint4(w[4], w[5], w[6], w[7]);
}

// ---------------- Kernel 5: group scan with global_load_lds DMA staging ------------
// Staging is linear (contiguous 24064 B/group, lane-major) -> exactly the
// global_load_lds pattern: 4 waves x 6 x 1KB DMA issued for group g+1 at the
// top of group g; __syncthreads at group end drains vmcnt. LDS buffers padded
// to 6144 words so the 512-B DMA overrun lands in pad; mask alloc +512 B.
// Stale sub-diagonal LDS garbage ORs only into already-consumed state words.
__global__ __launch_bounds__(256, 1) void k_scan(
    const unsigned int* __restrict__ mask,
    int* __restrict__ out_idx, int* __restrict__ out_cnt)
{
    __shared__ unsigned int rows[2][6144];    // 2 x 24576 B (24064 used + pad)
    __shared__ unsigned int sw_lds[2];
    int b    = blockIdx.x;
    int tid  = threadIdx.x;
    int wave = tid >> 6;
    int lane = tid & 63;
    const char* mbch = (const char*)(mask + (size_t)b * MROWS * ROWW);

    if (tid < 2) sw_lds[tid] = 0u;

    // DMA stage: group gidx -> rows[buf] (each wave: 6 x 1KB, lds base wave-uniform)
    auto stage = [&](int gidx, int buf) {
        const char* gb = mbch + (size_t)gidx * GBYTES + wave * 6144 + lane * 16;
        char* lb = (char*)rows[buf] + wave * 6144;
        #pragma unroll
        for (int i = 0; i < 6; i++)
            __builtin_amdgcn_global_load_lds(
                (const __attribute__((address_space(1))) unsigned int*)(gb + i * 1024),
                (__attribute__((address_space(3))) unsigned int*)(lb + i * 1024),
                16, 0, 0);
    };

    stage(0, 0);
    __syncthreads();                          // drains vmcnt -> rows[0] ready

    unsigned int st_word = 0u;                // thread tid owns state word tid (<ROWW)
    int cnt = 0;
    int* oi = out_idx + b * POST;

    for (int g = 0; g < NGRP; g++) {
        int cur = g & 1;
        bool have_next = (g + 1 < NGRP);

        // A: issue DMA for group g+1 (completes by this group's end barrier)
        if (have_next) stage(g + 1, cur ^ 1);

        // B: intra-group diagonal words (broadcast LDS reads)
        unsigned int tri[32];
        #pragma unroll
        for (int k = 0; k < 32; k++) tri[k] = rows[cur][k * ROWW + g];

        unsigned int sw = sw_lds[cur];

        // C: serial resolve with fused cap (replicated in all threads)
        int need_n = POST - cnt;
        unsigned int valid = (g == NGRP - 1) ? 0xFFFFu : 0xFFFFFFFFu;
        unsigned int alive = ~sw & valid;
        unsigned int km2 = 0u;
        int cum = 0;
        #pragma unroll
        for (int k = 0; k < 32; k++) {
            unsigned int bit = (alive >> k) & 1u;
            bit &= (cum < need_n) ? 1u : 0u;  // cap: dropped rows don't suppress
            cum += (int)bit;
            km2 |= bit << k;
            alive &= ~((0u - bit) & tri[k]);
        }

        // D: record kept indices (threads 0..31)
        if (tid < 32 && ((km2 >> tid) & 1u))
            oi[cnt + __popc(km2 & ((1u << tid) - 1u))] = g * 32 + tid;
        cnt += cum;

        // E: OR kept rows' word-tid into owned state
        if (tid < ROWW) {
            unsigned int acc = 0u;
            #pragma unroll
            for (int k = 0; k < 32; k++)
                acc |= rows[cur][k * ROWW + tid] & (0u - ((km2 >> k) & 1u));
            st_word |= acc;
        }

        // F: publish next group's decision word (owner thread)
        if (have_next && tid == g + 1) sw_lds[(g + 1) & 1] = st_word;

        __syncthreads();                      // waits DMA (vmcnt) + LDS ops
    }
    if (tid == 0) out_cnt[b] = cnt;
}

// ---------------- Kernel 6: compact + clip output ----------------
__global__ __launch_bounds__(256) void k_out(
    const float4* __restrict__ sboxes, const float* __restrict__ sscores,
    const int* __restrict__ out_idx, const int* __restrict__ out_cnt,
    float* __restrict__ out)
{
    int t = blockIdx.x * 256 + threadIdx.x;
    if (t >= BATCH * POST) return;
    int b = t / POST;
    int r = t - b * POST;
    float4 v = make_float4(0, 0, 0, 0);
    float sc = 0.f;
    if (r < out_cnt[b]) {
        int i = out_idx[b * POST + r];
        float4 bx = sboxes[(size_t)b * PRE + i];
        v.x = fminf(fmaxf(bx.x, 0.f), 1.f);
        v.y = fminf(fmaxf(bx.y, 0.f), 1.f);
        v.z = fminf(fmaxf(bx.z, 0.f), 1.f);
        v.w = fminf(fmaxf(bx.w, 0.f), 1.f);
        sc = sscores[(size_t)b * PRE + i];
    }
    ((float4*)out)[t] = v;                  // roi_bboxes
    out[(size_t)BATCH * POST * 4 + t] = sc; // roi_scores
}

// ---------------- host ----------------
extern "C" void kernel_launch(void* const* d_in, const int* in_sizes, int n_in,
                              void* d_out, int out_size, void* d_ws, size_t ws_size,
                              hipStream_t stream)
{
    const float* deltas  = (const float*)d_in[0];
    const float* probs   = (const float*)d_in[1];
    const float* anchors = (const float*)d_in[2];
    float* out = (float*)d_out;

    char* ws = (char*)d_ws;
    size_t off = 0;
    auto alloc = [&](size_t bytes) {
        size_t o = off;
        off = (off + bytes + 255) & ~(size_t)255;
        return o;
    };
    float4* boxes            = (float4*)(ws + alloc((size_t)BATCH * N_ANC * 16));
    unsigned long long* keys = (unsigned long long*)(ws + alloc((size_t)BATCH * SORT_N * 8));
    float4* sboxes           = (float4*)(ws + alloc((size_t)BATCH * PRE * 16));
    float* sscores           = (float*)(ws + alloc((size_t)BATCH * PRE * 4));
    unsigned int* mask       = (unsigned int*)(ws + alloc((size_t)BATCH * MROWS * ROWW * 4 + 512));
    int* oidx                = (int*)(ws + alloc((size_t)BATCH * POST * 4));
    int* ocnt                = (int*)(ws + alloc((size_t)BATCH * 4));

    k_decode<<<(BATCH * SORT_N + 255) / 256, 256, 0, stream>>>(deltas, probs, anchors, boxes, keys);
    k_sort_chunk<<<BATCH * 2, 1024, 0, stream>>>(keys);
    k_sort_merge<<<BATCH, 1024, 0, stream>>>(keys);
    k_gather<<<(BATCH * PRE + 255) / 256, 256, 0, stream>>>(keys, boxes, probs, sboxes, sscores);
    k_iou<<<dim3(24, 24, BATCH), 256, 0, stream>>>(sboxes, mask);
    k_scan<<<BATCH, 256, 0, stream>>>(mask, oidx, ocnt);
    k_out<<<(BATCH * POST + 255) / 256, 256, 0, stream>>>(sboxes, sscores, oidx, ocnt, out);
}